// Round 3
// baseline (434.988 us; speedup 1.0000x reference)
//
#include <hip/hip_runtime.h>
#include <hip/hip_bf16.h>

#define S_LEN 2048
#define HID 4096
#define NH 32
#define NKV 8
#define HD 128

typedef __attribute__((ext_vector_type(4))) float f32x4;
typedef __attribute__((ext_vector_type(8))) __bf16 bf16x8;
typedef __attribute__((ext_vector_type(8))) unsigned short u16x8;
typedef __attribute__((ext_vector_type(4))) unsigned short u16x4;

static __device__ __forceinline__ unsigned short f2bf(float x) {
  return __builtin_bit_cast(unsigned short, __float2bfloat16(x));
}
static __device__ __forceinline__ float bf2f(unsigned short u) {
  return __builtin_bit_cast(float, (unsigned int)u << 16);
}
static __device__ __forceinline__ void gld16(const unsigned short* g, unsigned short* l) {
  __builtin_amdgcn_global_load_lds(
      (const __attribute__((address_space(1))) unsigned int*)g,
      (__attribute__((address_space(3))) unsigned int*)l, 16, 0, 0);
}

// ---------------- fp32 -> bf16 bulk convert ----------------
__global__ void f2bf_kernel(const float* __restrict__ in, unsigned short* __restrict__ out, int n8) {
  int i = blockIdx.x * 256 + threadIdx.x;
  if (i >= n8) return;
  f32x4 a = ((const f32x4*)in)[(size_t)i * 2];
  f32x4 b = ((const f32x4*)in)[(size_t)i * 2 + 1];
  u16x8 w;
#pragma unroll
  for (int j = 0; j < 4; ++j) {
    w[j] = f2bf(a[j]);
    w[4 + j] = f2bf(b[j]);
  }
  ((u16x8*)out)[(size_t)i] = w;
}

// ---------------- RoPE table ----------------
__global__ void rope_table(float* cs) {
  int idx = blockIdx.x * blockDim.x + threadIdx.x;
  if (idx >= S_LEN * 64) return;
  int d = idx & 63;
  int p = idx >> 6;
  float invf = exp2f(-(float)d * (19.9315685693241741f / 64.0f));  // theta^-d/64
  float ang = (float)p * invf;
  cs[idx] = cosf(ang);
  cs[S_LEN * 64 + idx] = sinf(ang);
}

// ---------------- GEMM: C[2048,N] = A[2048,4096] @ W[N,4096]^T ----------------
// 128x128 tile, BK=32, global_load_lds(16B), double-buffered LDS, 1 barrier/K-step.
// Wave's 4 B-frags cover cols {wc*32+[0,16), +16, +64, +80} so rope pairs (d,d+64)
// live in the same wave (frags ni and ni+2).
// MODE 0: Cout fp32 (out-projection). MODE 1: fused QKV epilogue with RoPE;
// Q pre-scaled by 1/sqrt(128)*log2(e); V written transposed [n][S].
template <int MODE>
__global__ __launch_bounds__(256) void gemm_nt(
    const unsigned short* __restrict__ A, const unsigned short* __restrict__ W,
    const float* __restrict__ bq, const float* __restrict__ bk, const float* __restrict__ bv,
    const float* __restrict__ cs,
    unsigned short* __restrict__ Qb, unsigned short* __restrict__ Kb,
    unsigned short* __restrict__ VTb, float* __restrict__ Cout) {
  __shared__ unsigned short As[2][4096];  // [buf][128 rows][32] linear
  __shared__ unsigned short Bs[2][4096];
  int lin = blockIdx.x + 16 * blockIdx.y;
  int cpx = (16 * gridDim.y) >> 3;
  int swz = (lin & 7) * cpx + (lin >> 3);
  const int m0 = (swz & 15) * 128;
  const int n0 = (swz >> 4) * 128;
  const int tid = threadIdx.x, lane = tid & 63, wv = tid >> 6;
  const int wr = wv >> 1, wc = wv & 1;
  const int lr = lane & 15, lg = lane >> 4;
  const int srow = lane >> 2, skk = (lane & 3) * 8;

  const unsigned short* Ag0 = A + (size_t)(m0 + wv * 32 + srow) * HID + skk;
  const unsigned short* Ag1 = Ag0 + (size_t)16 * HID;
  const unsigned short* Wg0 = W + (size_t)(n0 + wv * 32 + srow) * HID + skk;
  const unsigned short* Wg1 = Wg0 + (size_t)16 * HID;

  f32x4 acc[4][4] = {};

  const int NK = HID / 32;
  // prologue: stage tile 0 into buf 0
  gld16(Ag0, &As[0][wv * 1024]);
  gld16(Ag1, &As[0][wv * 1024 + 512]);
  gld16(Wg0, &Bs[0][wv * 1024]);
  gld16(Wg1, &Bs[0][wv * 1024 + 512]);
  __syncthreads();

  int cur = 0;
  for (int kt = 0; kt < NK; ++kt) {
    if (kt + 1 < NK) {  // stage next tile into other buffer; latency hides under MFMA
      const int ko = (kt + 1) * 32;
      gld16(Ag0 + ko, &As[cur ^ 1][wv * 1024]);
      gld16(Ag1 + ko, &As[cur ^ 1][wv * 1024 + 512]);
      gld16(Wg0 + ko, &Bs[cur ^ 1][wv * 1024]);
      gld16(Wg1 + ko, &Bs[cur ^ 1][wv * 1024 + 512]);
    }
    bf16x8 af[4], bfr[4];
#pragma unroll
    for (int i = 0; i < 4; ++i)
      af[i] = *(const bf16x8*)&As[cur][(wr * 64 + i * 16 + lr) * 32 + lg * 8];
#pragma unroll
    for (int i = 0; i < 4; ++i)
      bfr[i] = *(const bf16x8*)&Bs[cur][(wc * 32 + (i & 1) * 16 + (i >> 1) * 64 + lr) * 32 + lg * 8];
#pragma unroll
    for (int mi = 0; mi < 4; ++mi)
#pragma unroll
      for (int ni = 0; ni < 4; ++ni)
        acc[mi][ni] = __builtin_amdgcn_mfma_f32_16x16x32_bf16(af[mi], bfr[ni], acc[mi][ni], 0, 0, 0);
    __syncthreads();  // drains vmcnt (next stage) + guards buffer reuse
    cur ^= 1;
  }

  if (MODE == 0) {
#pragma unroll
    for (int mi = 0; mi < 4; ++mi) {
      int row = m0 + wr * 64 + mi * 16 + lg * 4;
#pragma unroll
      for (int ni = 0; ni < 4; ++ni) {
        int col = n0 + wc * 32 + (ni & 1) * 16 + (ni >> 1) * 64 + lr;
#pragma unroll
        for (int j = 0; j < 4; ++j)
          Cout[(size_t)(row + j) * HID + col] = acc[mi][ni][j];
      }
    }
  } else {
    if (n0 < 5120) {
      // Q (scaled) or K: fused RoPE in fp32
      const bool isQ = (n0 < 4096);
      const float SC = isQ ? (0.08838834764831845f * 1.44269504088896340f) : 1.0f;
      const float* bptr = isQ ? bq : bk;
      unsigned short* obuf = isQ ? Qb : Kb;
      const int cb = isQ ? n0 : n0 - 4096;
#pragma unroll
      for (int ni = 0; ni < 2; ++ni) {
        int c1 = cb + wc * 32 + ni * 16 + lr;  // local col, d1 = c1&127 in [0,64)
        int head = c1 >> 7, d1 = c1 & 127;
        float bb1 = bptr[c1], bb2 = bptr[c1 + 64];
#pragma unroll
        for (int mi = 0; mi < 4; ++mi) {
          int row = m0 + wr * 64 + mi * 16 + lg * 4;
#pragma unroll
          for (int j = 0; j < 4; ++j) {
            int pos = row + j;
            float cosv = cs[pos * 64 + d1];
            float sinv = cs[S_LEN * 64 + pos * 64 + d1];
            float x1 = acc[mi][ni][j] + bb1;
            float x2 = acc[mi][ni + 2][j] + bb2;
            obuf[((size_t)head * S_LEN + pos) * HD + d1] = f2bf((x1 * cosv - x2 * sinv) * SC);
            obuf[((size_t)head * S_LEN + pos) * HD + d1 + 64] = f2bf((x2 * cosv + x1 * sinv) * SC);
          }
        }
      }
    } else {
      // V transposed [col][S]
#pragma unroll
      for (int ni = 0; ni < 4; ++ni) {
        int c = n0 - 5120 + wc * 32 + (ni & 1) * 16 + (ni >> 1) * 64 + lr;
        float bb = bv[c];
#pragma unroll
        for (int mi = 0; mi < 4; ++mi) {
          int row = m0 + wr * 64 + mi * 16 + lg * 4;
          u16x4 pk;
#pragma unroll
          for (int j = 0; j < 4; ++j) pk[j] = f2bf(acc[mi][ni][j] + bb);
          *(u16x4*)&VTb[(size_t)c * S_LEN + row] = pk;
        }
      }
    }
  }
}

// ---------------- Flash attention ----------------
// grid (8, 32): 256 blocks, 8 waves, QBLK=128 (16 rows/wave), KVBLK=64.
// Block p handles q-tiles p and 15-p (34 KV tiles each -> balanced).
// Q pre-scaled; defer-max (T13); reg prefetch of next K/V tile (T14).
__global__ __launch_bounds__(512) void attn_fwd(const unsigned short* __restrict__ Qb,
                                                const unsigned short* __restrict__ Kb,
                                                const unsigned short* __restrict__ VTb,
                                                unsigned short* __restrict__ Ob) {
  __shared__ unsigned short Kl[64][136];
  __shared__ unsigned short Vt[128][72];
  __shared__ unsigned short Pl[8][16][72];
  int lin = blockIdx.x + 8 * blockIdx.y;
  int swz = (lin & 7) * 32 + (lin >> 3);  // each XCD owns 4 q-heads = 1 kv-head
  const int pair = swz & 7;
  const int h = swz >> 3;
  const int kh = h >> 2;
  const int tid = threadIdx.x, lane = tid & 63, wv = tid >> 6;
  const int lr = lane & 15, lg = lane >> 4;
  // staging: 512 threads, 2 chunks each
  const int krow = tid >> 4, koff = (tid & 15) * 8;   // K rows krow, krow+32
  const int vrow = tid >> 3, voff = (tid & 7) * 8;    // V rows vrow, vrow+64
  const unsigned short* Kbase = Kb + (size_t)kh * S_LEN * HD;
  const unsigned short* Vbase = VTb + (size_t)kh * HD * S_LEN;

  for (int half = 0; half < 2; ++half) {
    const int qt = half ? 15 - pair : pair;
    const int q0 = qt * 128;
    const int nt = 2 * qt + 2;
    bf16x8 qf[4];
    {
      const unsigned short* qp = Qb + ((size_t)h * S_LEN + q0 + wv * 16 + lr) * HD + lg * 8;
#pragma unroll
      for (int s = 0; s < 4; ++s) qf[s] = *(const bf16x8*)(qp + s * 32);
    }
    f32x4 o[8];
#pragma unroll
    for (int i = 0; i < 8; ++i) o[i] = f32x4{0.f, 0.f, 0.f, 0.f};
    float mrow[4] = {-1e30f, -1e30f, -1e30f, -1e30f};
    float lrow[4] = {0.f, 0.f, 0.f, 0.f};

    u16x8 kreg[2], vreg[2];
    {
      const unsigned short* kp = Kbase + (size_t)krow * HD + koff;
      const unsigned short* vp = Vbase + (size_t)vrow * S_LEN + voff;
      kreg[0] = *(const u16x8*)kp;
      kreg[1] = *(const u16x8*)(kp + (size_t)32 * HD);
      vreg[0] = *(const u16x8*)vp;
      vreg[1] = *(const u16x8*)(vp + (size_t)64 * S_LEN);
    }
    __syncthreads();  // prior half's LDS readers done
    *(u16x8*)&Kl[krow][koff] = kreg[0];
    *(u16x8*)&Kl[krow + 32][koff] = kreg[1];
    *(u16x8*)&Vt[vrow][voff] = vreg[0];
    *(u16x8*)&Vt[vrow + 64][voff] = vreg[1];
    __syncthreads();

    for (int t = 0; t < nt; ++t) {
      if (t + 1 < nt) {  // T14: prefetch next tile into regs
        const unsigned short* kp = Kbase + ((size_t)(t + 1) * 64 + krow) * HD + koff;
        const unsigned short* vp = Vbase + (size_t)vrow * S_LEN + (t + 1) * 64 + voff;
        kreg[0] = *(const u16x8*)kp;
        kreg[1] = *(const u16x8*)(kp + (size_t)32 * HD);
        vreg[0] = *(const u16x8*)vp;
        vreg[1] = *(const u16x8*)(vp + (size_t)64 * S_LEN);
      }
      const int c0 = t * 64;
      const bool active = (c0 <= q0 + wv * 16 + 15);  // wave-uniform: skip fully-masked
      if (active) {
        f32x4 sf[4];
        __builtin_amdgcn_s_setprio(1);
#pragma unroll
        for (int c = 0; c < 4; ++c) {
          f32x4 s = {0.f, 0.f, 0.f, 0.f};
#pragma unroll
          for (int ss = 0; ss < 4; ++ss) {
            bf16x8 kf = *(const bf16x8*)&Kl[c * 16 + lr][ss * 32 + lg * 8];
            s = __builtin_amdgcn_mfma_f32_16x16x32_bf16(qf[ss], kf, s, 0, 0, 0);
          }
          sf[c] = s;
        }
        __builtin_amdgcn_s_setprio(0);

        if (t >= 2 * qt) {  // diagonal tiles only
#pragma unroll
          for (int c = 0; c < 4; ++c)
#pragma unroll
            for (int j = 0; j < 4; ++j)
              if ((c0 + c * 16 + lr) > (q0 + wv * 16 + lg * 4 + j)) sf[c][j] = -1e30f;
        }
        float tmax[4] = {-1e30f, -1e30f, -1e30f, -1e30f};
#pragma unroll
        for (int c = 0; c < 4; ++c)
#pragma unroll
          for (int j = 0; j < 4; ++j) tmax[j] = fmaxf(tmax[j], sf[c][j]);
#pragma unroll
        for (int dlt = 1; dlt < 16; dlt <<= 1)
#pragma unroll
          for (int j = 0; j < 4; ++j)
            tmax[j] = fmaxf(tmax[j], __shfl_xor(tmax[j], dlt, 64));

        // T13 defer-max: only rescale when max grows materially
        bool need = (tmax[0] > mrow[0] + 8.f) || (tmax[1] > mrow[1] + 8.f) ||
                    (tmax[2] > mrow[2] + 8.f) || (tmax[3] > mrow[3] + 8.f);
        if (__any(need)) {
          float alpha[4];
#pragma unroll
          for (int j = 0; j < 4; ++j) {
            float mn = fmaxf(mrow[j], tmax[j]);
            alpha[j] = exp2f(mrow[j] - mn);
            mrow[j] = mn;
          }
#pragma unroll
          for (int f = 0; f < 8; ++f)
#pragma unroll
            for (int j = 0; j < 4; ++j) o[f][j] *= alpha[j];
#pragma unroll
          for (int j = 0; j < 4; ++j) lrow[j] *= alpha[j];
        }
        float tsum[4] = {0.f, 0.f, 0.f, 0.f};
#pragma unroll
        for (int c = 0; c < 4; ++c)
#pragma unroll
          for (int j = 0; j < 4; ++j) {
            float pv = exp2f(sf[c][j] - mrow[j]);
            tsum[j] += pv;
            Pl[wv][lg * 4 + j][(c * 16 + lr) ^ ((lg & 2) << 2)] = f2bf(pv);
          }
#pragma unroll
        for (int dlt = 1; dlt < 16; dlt <<= 1)
#pragma unroll
          for (int j = 0; j < 4; ++j) tsum[j] += __shfl_xor(tsum[j], dlt, 64);
#pragma unroll
        for (int j = 0; j < 4; ++j) lrow[j] += tsum[j];

        // PV
        __builtin_amdgcn_s_setprio(1);
#pragma unroll
        for (int ks = 0; ks < 2; ++ks) {
          bf16x8 pa = *(const bf16x8*)&Pl[wv][lr][(ks * 32 + lg * 8) ^ (lr & 8)];
#pragma unroll
          for (int df = 0; df < 8; ++df) {
            bf16x8 vb = *(const bf16x8*)&Vt[df * 16 + lr][ks * 32 + lg * 8];
            o[df] = __builtin_amdgcn_mfma_f32_16x16x32_bf16(pa, vb, o[df], 0, 0, 0);
          }
        }
        __builtin_amdgcn_s_setprio(0);
      }

      if (t + 1 < nt) {
        __syncthreads();  // all waves done reading current tile
        *(u16x8*)&Kl[krow][koff] = kreg[0];
        *(u16x8*)&Kl[krow + 32][koff] = kreg[1];
        *(u16x8*)&Vt[vrow][voff] = vreg[0];
        *(u16x8*)&Vt[vrow + 64][voff] = vreg[1];
        __syncthreads();
      }
    }

#pragma unroll
    for (int j = 0; j < 4; ++j) {
      float inv = 1.0f / lrow[j];
      int row = q0 + wv * 16 + lg * 4 + j;
#pragma unroll
      for (int df = 0; df < 8; ++df)
        Ob[(size_t)row * (NH * HD) + h * HD + df * 16 + lr] = f2bf(o[df][j] * inv);
    }
  }
}

// ---------------- launch ----------------
extern "C" void kernel_launch(void* const* d_in, const int* in_sizes, int n_in,
                              void* d_out, int out_size, void* d_ws, size_t ws_size,
                              hipStream_t stream) {
  const float* hidden = (const float*)d_in[0];
  const float* wq = (const float*)d_in[1];
  const float* bq = (const float*)d_in[2];
  const float* wk = (const float*)d_in[3];
  const float* bk = (const float*)d_in[4];
  const float* wv = (const float*)d_in[5];
  const float* bv = (const float*)d_in[6];
  const float* wo = (const float*)d_in[7];
  float* out = (float*)d_out;

  char* p = (char*)d_ws;
  float* cs = (float*)p;                      p += (size_t)1 << 20;
  unsigned short* hb = (unsigned short*)p;    p += (size_t)16 << 20;
  unsigned short* Qb = (unsigned short*)p;    p += (size_t)16 << 20;
  unsigned short* Kbuf = (unsigned short*)p;  p += (size_t)4 << 20;
  unsigned short* VTb = (unsigned short*)p;   p += (size_t)4 << 20;
  unsigned short* attno = (unsigned short*)p; p += (size_t)16 << 20;
  unsigned short* wbuf = (unsigned short*)p;  // 48 MB reused (qkv weights, then wo)

  hipLaunchKernelGGL(rope_table, dim3(512), dim3(256), 0, stream, cs);
  hipLaunchKernelGGL(f2bf_kernel, dim3(4096), dim3(256), 0, stream, hidden, hb, S_LEN * HID / 8);
  hipLaunchKernelGGL(f2bf_kernel, dim3(8192), dim3(256), 0, stream, wq, wbuf, 4096 * HID / 8);
  hipLaunchKernelGGL(f2bf_kernel, dim3(2048), dim3(256), 0, stream, wk, wbuf + (size_t)4096 * HID, 1024 * HID / 8);
  hipLaunchKernelGGL(f2bf_kernel, dim3(2048), dim3(256), 0, stream, wv, wbuf + (size_t)5120 * HID, 1024 * HID / 8);
  hipLaunchKernelGGL((gemm_nt<1>), dim3(16, 48), dim3(256), 0, stream,
                     hb, wbuf, bq, bk, bv, cs, Qb, Kbuf, VTb, (float*)nullptr);
  hipLaunchKernelGGL(attn_fwd, dim3(8, 32), dim3(512), 0, stream, Qb, Kbuf, VTb, attno);
  hipLaunchKernelGGL(f2bf_kernel, dim3(8192), dim3(256), 0, stream, wo, wbuf, 4096 * HID / 8);
  hipLaunchKernelGGL((gemm_nt<0>), dim3(16, 32), dim3(256), 0, stream,
                     attno, wbuf, (const float*)nullptr, (const float*)nullptr, (const float*)nullptr,
                     (const float*)nullptr, (unsigned short*)nullptr, (unsigned short*)nullptr,
                     (unsigned short*)nullptr, out);
}

// Round 4
// 410.026 us; speedup vs baseline: 1.0609x; 1.0609x over previous
//
#include <hip/hip_runtime.h>
#include <hip/hip_bf16.h>

#define S_LEN 2048
#define HID 4096
#define NH 32
#define NKV 8
#define HD 128

typedef __attribute__((ext_vector_type(4))) float f32x4;
typedef __attribute__((ext_vector_type(8))) __bf16 bf16x8;
typedef __attribute__((ext_vector_type(8))) unsigned short u16x8;
typedef __attribute__((ext_vector_type(4))) unsigned short u16x4;

static __device__ __forceinline__ unsigned short f2bf(float x) {
  return __builtin_bit_cast(unsigned short, __float2bfloat16(x));
}
static __device__ __forceinline__ float bf2f(unsigned short u) {
  return __builtin_bit_cast(float, (unsigned int)u << 16);
}
static __device__ __forceinline__ void gld16(const unsigned short* g, unsigned short* l) {
  __builtin_amdgcn_global_load_lds(
      (const __attribute__((address_space(1))) unsigned int*)g,
      (__attribute__((address_space(3))) unsigned int*)l, 16, 0, 0);
}

// ---------------- fp32 -> bf16 bulk convert ----------------
__global__ void f2bf_kernel(const float* __restrict__ in, unsigned short* __restrict__ out, int n8) {
  int i = blockIdx.x * 256 + threadIdx.x;
  if (i >= n8) return;
  f32x4 a = ((const f32x4*)in)[(size_t)i * 2];
  f32x4 b = ((const f32x4*)in)[(size_t)i * 2 + 1];
  u16x8 w;
#pragma unroll
  for (int j = 0; j < 4; ++j) {
    w[j] = f2bf(a[j]);
    w[4 + j] = f2bf(b[j]);
  }
  ((u16x8*)out)[(size_t)i] = w;
}

// ---------------- RoPE table ----------------
__global__ void rope_table(float* cs) {
  int idx = blockIdx.x * blockDim.x + threadIdx.x;
  if (idx >= S_LEN * 64) return;
  int d = idx & 63;
  int p = idx >> 6;
  float invf = exp2f(-(float)d * (19.9315685693241741f / 64.0f));  // theta^-d/64
  float ang = (float)p * invf;
  cs[idx] = cosf(ang);
  cs[S_LEN * 64 + idx] = sinf(ang);
}

// ---------------- GEMM: C[2048,N] = A[2048,4096] @ W[N,4096]^T ----------------
// m97 structure (PROVEN 852 TF here, round 2): 128x128 tile, BK=32, single LDS
// buffer, global_load_lds(16B), 2 barriers/K-step. Explicit dbuf REGRESSED to
// ~480 TF (round 3) — do not reintroduce.
// Wave's 4 B-frags cover cols {wc*32+[0,16), +16, +64, +80} so rope pairs
// (d, d+64) live in frags ni and ni+2 of the same wave.
// MODE 0: Cout fp32 (out-projection). MODE 1: fused QKV epilogue with RoPE;
// Q pre-scaled by 1/sqrt(128)*log2(e); V written transposed [n][S].
template <int MODE>
__global__ __launch_bounds__(256) void gemm_nt(
    const unsigned short* __restrict__ A, const unsigned short* __restrict__ W,
    const float* __restrict__ bq, const float* __restrict__ bk, const float* __restrict__ bv,
    const float* __restrict__ cs,
    unsigned short* __restrict__ Qb, unsigned short* __restrict__ Kb,
    unsigned short* __restrict__ VTb, float* __restrict__ Cout) {
  __shared__ unsigned short As[4096];  // [128 rows][32] linear
  __shared__ unsigned short Bs[4096];
  int lin = blockIdx.x + 16 * blockIdx.y;
  int cpx = (16 * gridDim.y) >> 3;
  int swz = (lin & 7) * cpx + (lin >> 3);
  const int m0 = (swz & 15) * 128;
  const int n0 = (swz >> 4) * 128;
  const int tid = threadIdx.x, lane = tid & 63, wv = tid >> 6;
  const int wr = wv >> 1, wc = wv & 1;
  const int lr = lane & 15, lg = lane >> 4;
  const int srow = lane >> 2, skk = (lane & 3) * 8;

  const unsigned short* Ag0 = A + (size_t)(m0 + wv * 32 + srow) * HID + skk;
  const unsigned short* Ag1 = Ag0 + (size_t)16 * HID;
  const unsigned short* Wg0 = W + (size_t)(n0 + wv * 32 + srow) * HID + skk;
  const unsigned short* Wg1 = Wg0 + (size_t)16 * HID;
  unsigned short* Al0 = As + wv * 1024;  // wave-uniform LDS slice bases
  unsigned short* Al1 = As + wv * 1024 + 512;
  unsigned short* Bl0 = Bs + wv * 1024;
  unsigned short* Bl1 = Bs + wv * 1024 + 512;

  f32x4 acc[4][4] = {};

  for (int kt = 0; kt < HID / 32; ++kt) {
    const int ko = kt * 32;
    gld16(Ag0 + ko, Al0);
    gld16(Ag1 + ko, Al1);
    gld16(Wg0 + ko, Bl0);
    gld16(Wg1 + ko, Bl1);
    __syncthreads();  // drains vmcnt -> tile visible
    bf16x8 af[4], bfr[4];
#pragma unroll
    for (int i = 0; i < 4; ++i)
      af[i] = *(const bf16x8*)&As[(wr * 64 + i * 16 + lr) * 32 + lg * 8];
#pragma unroll
    for (int i = 0; i < 4; ++i)
      bfr[i] = *(const bf16x8*)&Bs[(wc * 32 + (i & 1) * 16 + (i >> 1) * 64 + lr) * 32 + lg * 8];
#pragma unroll
    for (int mi = 0; mi < 4; ++mi)
#pragma unroll
      for (int ni = 0; ni < 4; ++ni)
        acc[mi][ni] = __builtin_amdgcn_mfma_f32_16x16x32_bf16(af[mi], bfr[ni], acc[mi][ni], 0, 0, 0);
    __syncthreads();  // reads done -> next stage may overwrite
  }

  if (MODE == 0) {
#pragma unroll
    for (int mi = 0; mi < 4; ++mi) {
      int row = m0 + wr * 64 + mi * 16 + lg * 4;
#pragma unroll
      for (int ni = 0; ni < 4; ++ni) {
        int col = n0 + wc * 32 + (ni & 1) * 16 + (ni >> 1) * 64 + lr;
#pragma unroll
        for (int j = 0; j < 4; ++j)
          Cout[(size_t)(row + j) * HID + col] = acc[mi][ni][j];
      }
    }
  } else {
    if (n0 < 5120) {
      // Q (scaled) or K: fused RoPE in fp32
      const bool isQ = (n0 < 4096);
      const float SC = isQ ? (0.08838834764831845f * 1.44269504088896340f) : 1.0f;
      const float* bptr = isQ ? bq : bk;
      unsigned short* obuf = isQ ? Qb : Kb;
      const int cb = isQ ? n0 : n0 - 4096;
#pragma unroll
      for (int ni = 0; ni < 2; ++ni) {
        int c1 = cb + wc * 32 + ni * 16 + lr;  // d1 = c1&127 in [0,64)
        int head = c1 >> 7, d1 = c1 & 127;
        float bb1 = bptr[c1], bb2 = bptr[c1 + 64];
#pragma unroll
        for (int mi = 0; mi < 4; ++mi) {
          int row = m0 + wr * 64 + mi * 16 + lg * 4;
#pragma unroll
          for (int j = 0; j < 4; ++j) {
            int pos = row + j;
            float cosv = cs[pos * 64 + d1];
            float sinv = cs[S_LEN * 64 + pos * 64 + d1];
            float x1 = acc[mi][ni][j] + bb1;
            float x2 = acc[mi][ni + 2][j] + bb2;
            obuf[((size_t)head * S_LEN + pos) * HD + d1] = f2bf((x1 * cosv - x2 * sinv) * SC);
            obuf[((size_t)head * S_LEN + pos) * HD + d1 + 64] = f2bf((x2 * cosv + x1 * sinv) * SC);
          }
        }
      }
    } else {
      // V transposed [col][S]
#pragma unroll
      for (int ni = 0; ni < 4; ++ni) {
        int c = n0 - 5120 + wc * 32 + (ni & 1) * 16 + (ni >> 1) * 64 + lr;
        float bb = bv[c];
#pragma unroll
        for (int mi = 0; mi < 4; ++mi) {
          int row = m0 + wr * 64 + mi * 16 + lg * 4;
          u16x4 pk;
#pragma unroll
          for (int j = 0; j < 4; ++j) pk[j] = f2bf(acc[mi][ni][j] + bb);
          *(u16x4*)&VTb[(size_t)c * S_LEN + row] = pk;
        }
      }
    }
  }
}

// ---------------- Flash attention ----------------
// grid (8, 32): 256 blocks, 8 waves, QBLK=128 (16 rows/wave), KVBLK=64.
// Block p handles q-tiles p and 15-p (34 KV tiles each -> balanced).
// Q pre-scaled; defer-max (T13); reg prefetch of next K/V tile (T14).
__global__ __launch_bounds__(512) void attn_fwd(const unsigned short* __restrict__ Qb,
                                                const unsigned short* __restrict__ Kb,
                                                const unsigned short* __restrict__ VTb,
                                                unsigned short* __restrict__ Ob) {
  __shared__ unsigned short Kl[64][136];
  __shared__ unsigned short Vt[128][72];
  __shared__ unsigned short Pl[8][16][72];
  int lin = blockIdx.x + 8 * blockIdx.y;
  int swz = (lin & 7) * 32 + (lin >> 3);  // each XCD owns 4 q-heads = 1 kv-head
  const int pair = swz & 7;
  const int h = swz >> 3;
  const int kh = h >> 2;
  const int tid = threadIdx.x, lane = tid & 63, wv = tid >> 6;
  const int lr = lane & 15, lg = lane >> 4;
  const int krow = tid >> 4, koff = (tid & 15) * 8;   // K rows krow, krow+32
  const int vrow = tid >> 3, voff = (tid & 7) * 8;    // V rows vrow, vrow+64
  const unsigned short* Kbase = Kb + (size_t)kh * S_LEN * HD;
  const unsigned short* Vbase = VTb + (size_t)kh * HD * S_LEN;

  for (int half = 0; half < 2; ++half) {
    const int qt = half ? 15 - pair : pair;
    const int q0 = qt * 128;
    const int nt = 2 * qt + 2;
    bf16x8 qf[4];
    {
      const unsigned short* qp = Qb + ((size_t)h * S_LEN + q0 + wv * 16 + lr) * HD + lg * 8;
#pragma unroll
      for (int s = 0; s < 4; ++s) qf[s] = *(const bf16x8*)(qp + s * 32);
    }
    f32x4 o[8];
#pragma unroll
    for (int i = 0; i < 8; ++i) o[i] = f32x4{0.f, 0.f, 0.f, 0.f};
    float mrow[4] = {-1e30f, -1e30f, -1e30f, -1e30f};
    float lrow[4] = {0.f, 0.f, 0.f, 0.f};

    u16x8 kreg[2], vreg[2];
    {
      const unsigned short* kp = Kbase + (size_t)krow * HD + koff;
      const unsigned short* vp = Vbase + (size_t)vrow * S_LEN + voff;
      kreg[0] = *(const u16x8*)kp;
      kreg[1] = *(const u16x8*)(kp + (size_t)32 * HD);
      vreg[0] = *(const u16x8*)vp;
      vreg[1] = *(const u16x8*)(vp + (size_t)64 * S_LEN);
    }
    __syncthreads();  // prior half's LDS readers done
    *(u16x8*)&Kl[krow][koff] = kreg[0];
    *(u16x8*)&Kl[krow + 32][koff] = kreg[1];
    *(u16x8*)&Vt[vrow][voff] = vreg[0];
    *(u16x8*)&Vt[vrow + 64][voff] = vreg[1];
    __syncthreads();

    for (int t = 0; t < nt; ++t) {
      if (t + 1 < nt) {  // T14: prefetch next tile into regs
        const unsigned short* kp = Kbase + ((size_t)(t + 1) * 64 + krow) * HD + koff;
        const unsigned short* vp = Vbase + (size_t)vrow * S_LEN + (t + 1) * 64 + voff;
        kreg[0] = *(const u16x8*)kp;
        kreg[1] = *(const u16x8*)(kp + (size_t)32 * HD);
        vreg[0] = *(const u16x8*)vp;
        vreg[1] = *(const u16x8*)(vp + (size_t)64 * S_LEN);
      }
      const int c0 = t * 64;
      const bool active = (c0 <= q0 + wv * 16 + 15);  // wave-uniform: skip fully-masked
      if (active) {
        f32x4 sf[4];
        __builtin_amdgcn_s_setprio(1);
#pragma unroll
        for (int c = 0; c < 4; ++c) {
          f32x4 s = {0.f, 0.f, 0.f, 0.f};
#pragma unroll
          for (int ss = 0; ss < 4; ++ss) {
            bf16x8 kf = *(const bf16x8*)&Kl[c * 16 + lr][ss * 32 + lg * 8];
            s = __builtin_amdgcn_mfma_f32_16x16x32_bf16(qf[ss], kf, s, 0, 0, 0);
          }
          sf[c] = s;
        }
        __builtin_amdgcn_s_setprio(0);

        if (t >= 2 * qt) {  // diagonal tiles only
#pragma unroll
          for (int c = 0; c < 4; ++c)
#pragma unroll
            for (int j = 0; j < 4; ++j)
              if ((c0 + c * 16 + lr) > (q0 + wv * 16 + lg * 4 + j)) sf[c][j] = -1e30f;
        }
        float tmax[4] = {-1e30f, -1e30f, -1e30f, -1e30f};
#pragma unroll
        for (int c = 0; c < 4; ++c)
#pragma unroll
          for (int j = 0; j < 4; ++j) tmax[j] = fmaxf(tmax[j], sf[c][j]);
#pragma unroll
        for (int dlt = 1; dlt < 16; dlt <<= 1)
#pragma unroll
          for (int j = 0; j < 4; ++j)
            tmax[j] = fmaxf(tmax[j], __shfl_xor(tmax[j], dlt, 64));

        // T13 defer-max: only rescale when max grows materially
        bool need = (tmax[0] > mrow[0] + 8.f) || (tmax[1] > mrow[1] + 8.f) ||
                    (tmax[2] > mrow[2] + 8.f) || (tmax[3] > mrow[3] + 8.f);
        if (__any(need)) {
          float alpha[4];
#pragma unroll
          for (int j = 0; j < 4; ++j) {
            float mn = fmaxf(mrow[j], tmax[j]);
            alpha[j] = exp2f(mrow[j] - mn);
            mrow[j] = mn;
          }
#pragma unroll
          for (int f = 0; f < 8; ++f)
#pragma unroll
            for (int j = 0; j < 4; ++j) o[f][j] *= alpha[j];
#pragma unroll
          for (int j = 0; j < 4; ++j) lrow[j] *= alpha[j];
        }
        float tsum[4] = {0.f, 0.f, 0.f, 0.f};
#pragma unroll
        for (int c = 0; c < 4; ++c)
#pragma unroll
          for (int j = 0; j < 4; ++j) {
            float pv = exp2f(sf[c][j] - mrow[j]);
            tsum[j] += pv;
            Pl[wv][lg * 4 + j][(c * 16 + lr) ^ ((lg & 2) << 2)] = f2bf(pv);
          }
#pragma unroll
        for (int dlt = 1; dlt < 16; dlt <<= 1)
#pragma unroll
          for (int j = 0; j < 4; ++j) tsum[j] += __shfl_xor(tsum[j], dlt, 64);
#pragma unroll
        for (int j = 0; j < 4; ++j) lrow[j] += tsum[j];

        // PV
        __builtin_amdgcn_s_setprio(1);
#pragma unroll
        for (int ks = 0; ks < 2; ++ks) {
          bf16x8 pa = *(const bf16x8*)&Pl[wv][lr][(ks * 32 + lg * 8) ^ (lr & 8)];
#pragma unroll
          for (int df = 0; df < 8; ++df) {
            bf16x8 vb = *(const bf16x8*)&Vt[df * 16 + lr][ks * 32 + lg * 8];
            o[df] = __builtin_amdgcn_mfma_f32_16x16x32_bf16(pa, vb, o[df], 0, 0, 0);
          }
        }
        __builtin_amdgcn_s_setprio(0);
      }

      if (t + 1 < nt) {
        __syncthreads();  // all waves done reading current tile
        *(u16x8*)&Kl[krow][koff] = kreg[0];
        *(u16x8*)&Kl[krow + 32][koff] = kreg[1];
        *(u16x8*)&Vt[vrow][voff] = vreg[0];
        *(u16x8*)&Vt[vrow + 64][voff] = vreg[1];
        __syncthreads();
      }
    }

#pragma unroll
    for (int j = 0; j < 4; ++j) {
      float inv = 1.0f / lrow[j];
      int row = q0 + wv * 16 + lg * 4 + j;
#pragma unroll
      for (int df = 0; df < 8; ++df)
        Ob[(size_t)row * (NH * HD) + h * HD + df * 16 + lr] = f2bf(o[df][j] * inv);
    }
  }
}

// ---------------- launch ----------------
extern "C" void kernel_launch(void* const* d_in, const int* in_sizes, int n_in,
                              void* d_out, int out_size, void* d_ws, size_t ws_size,
                              hipStream_t stream) {
  const float* hidden = (const float*)d_in[0];
  const float* wq = (const float*)d_in[1];
  const float* bq = (const float*)d_in[2];
  const float* wk = (const float*)d_in[3];
  const float* bk = (const float*)d_in[4];
  const float* wv = (const float*)d_in[5];
  const float* bv = (const float*)d_in[6];
  const float* wo = (const float*)d_in[7];
  float* out = (float*)d_out;

  char* p = (char*)d_ws;
  float* cs = (float*)p;                      p += (size_t)1 << 20;
  unsigned short* hb = (unsigned short*)p;    p += (size_t)16 << 20;
  unsigned short* Qb = (unsigned short*)p;    p += (size_t)16 << 20;
  unsigned short* Kbuf = (unsigned short*)p;  p += (size_t)4 << 20;
  unsigned short* VTb = (unsigned short*)p;   p += (size_t)4 << 20;
  unsigned short* attno = (unsigned short*)p; p += (size_t)16 << 20;
  unsigned short* wbuf = (unsigned short*)p;  // 48 MB reused (qkv weights, then wo)

  hipLaunchKernelGGL(rope_table, dim3(512), dim3(256), 0, stream, cs);
  hipLaunchKernelGGL(f2bf_kernel, dim3(4096), dim3(256), 0, stream, hidden, hb, S_LEN * HID / 8);
  hipLaunchKernelGGL(f2bf_kernel, dim3(8192), dim3(256), 0, stream, wq, wbuf, 4096 * HID / 8);
  hipLaunchKernelGGL(f2bf_kernel, dim3(2048), dim3(256), 0, stream, wk, wbuf + (size_t)4096 * HID, 1024 * HID / 8);
  hipLaunchKernelGGL(f2bf_kernel, dim3(2048), dim3(256), 0, stream, wv, wbuf + (size_t)5120 * HID, 1024 * HID / 8);
  hipLaunchKernelGGL((gemm_nt<1>), dim3(16, 48), dim3(256), 0, stream,
                     hb, wbuf, bq, bk, bv, cs, Qb, Kbuf, VTb, (float*)nullptr);
  hipLaunchKernelGGL(attn_fwd, dim3(8, 32), dim3(512), 0, stream, Qb, Kbuf, VTb, attno);
  hipLaunchKernelGGL(f2bf_kernel, dim3(8192), dim3(256), 0, stream, wo, wbuf, 4096 * HID / 8);
  hipLaunchKernelGGL((gemm_nt<0>), dim3(16, 32), dim3(256), 0, stream,
                     attno, wbuf, (const float*)nullptr, (const float*)nullptr, (const float*)nullptr,
                     (const float*)nullptr, (unsigned short*)nullptr, (unsigned short*)nullptr,
                     (unsigned short*)nullptr, out);
}

// Round 5
// 373.178 us; speedup vs baseline: 1.1656x; 1.0987x over previous
//
#include <hip/hip_runtime.h>
#include <hip/hip_bf16.h>

#define S_LEN 2048
#define HID 4096
#define NH 32
#define NKV 8
#define HD 128

typedef __attribute__((ext_vector_type(4))) float f32x4;
typedef __attribute__((ext_vector_type(8))) __bf16 bf16x8;
typedef __attribute__((ext_vector_type(8))) unsigned short u16x8;
typedef __attribute__((ext_vector_type(4))) unsigned short u16x4;

static __device__ __forceinline__ unsigned short f2bf(float x) {
  return __builtin_bit_cast(unsigned short, __float2bfloat16(x));
}
static __device__ __forceinline__ float bf2f(unsigned short u) {
  return __builtin_bit_cast(float, (unsigned int)u << 16);
}
static __device__ __forceinline__ void gld16(const unsigned short* g, unsigned short* l) {
  __builtin_amdgcn_global_load_lds(
      (const __attribute__((address_space(1))) unsigned int*)g,
      (__attribute__((address_space(3))) unsigned int*)l, 16, 0, 0);
}

// ---------------- fp32 -> bf16 bulk convert ----------------
__global__ void f2bf_kernel(const float* __restrict__ in, unsigned short* __restrict__ out, int n8) {
  int i = blockIdx.x * 256 + threadIdx.x;
  if (i >= n8) return;
  f32x4 a = ((const f32x4*)in)[(size_t)i * 2];
  f32x4 b = ((const f32x4*)in)[(size_t)i * 2 + 1];
  u16x8 w;
#pragma unroll
  for (int j = 0; j < 4; ++j) {
    w[j] = f2bf(a[j]);
    w[4 + j] = f2bf(b[j]);
  }
  ((u16x8*)out)[(size_t)i] = w;
}

// ---------------- RoPE table ----------------
__global__ void rope_table(float* cs) {
  int idx = blockIdx.x * blockDim.x + threadIdx.x;
  if (idx >= S_LEN * 64) return;
  int d = idx & 63;
  int p = idx >> 6;
  float invf = exp2f(-(float)d * (19.9315685693241741f / 64.0f));  // theta^-d/64
  float ang = (float)p * invf;
  cs[idx] = cosf(ang);
  cs[S_LEN * 64 + idx] = sinf(ang);
}

// ---------------- RoPE apply (in-place, bf16 [head][S][128], x scale) ----------------
__global__ void rope_apply(unsigned short* __restrict__ buf, const float* __restrict__ cs,
                           float scale, int total) {
  int idx = blockIdx.x * blockDim.x + threadIdx.x;
  if (idx >= total) return;  // total = nheads * S * 64
  int d = idx & 63;
  int hp = idx >> 6;
  int pos = hp & (S_LEN - 1);
  size_t base = (size_t)hp * HD;
  float c = cs[pos * 64 + d];
  float s = cs[S_LEN * 64 + pos * 64 + d];
  float x1 = bf2f(buf[base + d]);
  float x2 = bf2f(buf[base + 64 + d]);
  buf[base + d] = f2bf((x1 * c - x2 * s) * scale);
  buf[base + 64 + d] = f2bf((x2 * c + x1 * s) * scale);
}

// ---------------- GEMM: C[2048,N] = A[2048,4096] @ W[N,4096]^T ----------------
// EXACT round-2 structure (measured 852/563 TF here): 128x128 tile, BK=32,
// single LDS buffer, global_load_lds(16B), 2 barriers/K-step, simple epilogue.
// Round-3/4 variants (dbuf, B-frag remap, RoPE-fused epilogue) all REGRESSED
// (121->176/204 us) — do not reintroduce without within-round A/B.
// MODE 0: Cout fp32 [M][4096], no bias (out-projection)
// MODE 1: fused QKV epilogue -> Qb/Kb (bf16 [head][S][128], +bias), VTb ([n][S], +bias)
template <int MODE>
__global__ __launch_bounds__(256) void gemm_nt(
    const unsigned short* __restrict__ A, const unsigned short* __restrict__ W,
    const float* __restrict__ bq, const float* __restrict__ bk, const float* __restrict__ bv,
    unsigned short* __restrict__ Qb, unsigned short* __restrict__ Kb,
    unsigned short* __restrict__ VTb, float* __restrict__ Cout) {
  __shared__ unsigned short As[4096];  // [128 rows][32] linear
  __shared__ unsigned short Bs[4096];
  int lin = blockIdx.x + 16 * blockIdx.y;
  int cpx = (16 * gridDim.y) >> 3;
  int swz = (lin & 7) * cpx + (lin >> 3);
  const int m0 = (swz & 15) * 128;
  const int n0 = (swz >> 4) * 128;
  const int tid = threadIdx.x, lane = tid & 63, wv = tid >> 6;
  const int wr = wv >> 1, wc = wv & 1;
  const int lr = lane & 15, lg = lane >> 4;
  const int srow = lane >> 2, skk = (lane & 3) * 8;

  const unsigned short* Ag0 = A + (size_t)(m0 + wv * 32 + srow) * HID + skk;
  const unsigned short* Ag1 = Ag0 + (size_t)16 * HID;
  const unsigned short* Wg0 = W + (size_t)(n0 + wv * 32 + srow) * HID + skk;
  const unsigned short* Wg1 = Wg0 + (size_t)16 * HID;
  unsigned short* Al0 = As + wv * 1024;  // wave-uniform LDS slice bases
  unsigned short* Al1 = As + wv * 1024 + 512;
  unsigned short* Bl0 = Bs + wv * 1024;
  unsigned short* Bl1 = Bs + wv * 1024 + 512;

  f32x4 acc[4][4] = {};

  for (int kt = 0; kt < HID / 32; ++kt) {
    const int ko = kt * 32;
    gld16(Ag0 + ko, Al0);
    gld16(Ag1 + ko, Al1);
    gld16(Wg0 + ko, Bl0);
    gld16(Wg1 + ko, Bl1);
    __syncthreads();  // drains vmcnt -> tile visible
    bf16x8 af[4], bfr[4];
#pragma unroll
    for (int i = 0; i < 4; ++i)
      af[i] = *(const bf16x8*)&As[(wr * 64 + i * 16 + lr) * 32 + lg * 8];
#pragma unroll
    for (int i = 0; i < 4; ++i)
      bfr[i] = *(const bf16x8*)&Bs[(wc * 64 + i * 16 + lr) * 32 + lg * 8];
#pragma unroll
    for (int mi = 0; mi < 4; ++mi)
#pragma unroll
      for (int ni = 0; ni < 4; ++ni)
        acc[mi][ni] = __builtin_amdgcn_mfma_f32_16x16x32_bf16(af[mi], bfr[ni], acc[mi][ni], 0, 0, 0);
    __syncthreads();  // reads done -> next stage may overwrite
  }

  if (MODE == 0) {
#pragma unroll
    for (int mi = 0; mi < 4; ++mi) {
      int row = m0 + wr * 64 + mi * 16 + lg * 4;
#pragma unroll
      for (int ni = 0; ni < 4; ++ni) {
        int col = n0 + wc * 64 + ni * 16 + lr;
#pragma unroll
        for (int j = 0; j < 4; ++j)
          Cout[(size_t)(row + j) * HID + col] = acc[mi][ni][j];
      }
    }
  } else {
    unsigned short* obuf;
    const float* bptr;
    int cbase;
    bool transp = false;
    if (n0 < 4096) { obuf = Qb; bptr = bq; cbase = n0; }
    else if (n0 < 5120) { obuf = Kb; bptr = bk; cbase = n0 - 4096; }
    else { obuf = VTb; bptr = bv; cbase = n0 - 5120; transp = true; }
#pragma unroll
    for (int ni = 0; ni < 4; ++ni) {
      int c = cbase + wc * 64 + ni * 16 + lr;
      float bb = bptr[c];
      if (!transp) {
        int head = c >> 7, d = c & 127;
#pragma unroll
        for (int mi = 0; mi < 4; ++mi) {
          int row = m0 + wr * 64 + mi * 16 + lg * 4;
#pragma unroll
          for (int j = 0; j < 4; ++j)
            obuf[((size_t)head * S_LEN + row + j) * HD + d] = f2bf(acc[mi][ni][j] + bb);
        }
      } else {
#pragma unroll
        for (int mi = 0; mi < 4; ++mi) {
          int row = m0 + wr * 64 + mi * 16 + lg * 4;
          u16x4 pk;
#pragma unroll
          for (int j = 0; j < 4; ++j) pk[j] = f2bf(acc[mi][ni][j] + bb);
          *(u16x4*)&obuf[(size_t)c * S_LEN + row] = pk;
        }
      }
    }
  }
}

// ---------------- Flash attention ----------------
// grid (8, 32): 256 blocks, 8 waves, QBLK=128 (16 rows/wave), KVBLK=64.
// Block p handles q-tiles p and 15-p (34 KV tiles each -> balanced).
// Q pre-scaled (in rope_apply); defer-max (T13); reg prefetch (T14).
__global__ __launch_bounds__(512) void attn_fwd(const unsigned short* __restrict__ Qb,
                                                const unsigned short* __restrict__ Kb,
                                                const unsigned short* __restrict__ VTb,
                                                unsigned short* __restrict__ Ob) {
  __shared__ unsigned short Kl[64][136];
  __shared__ unsigned short Vt[128][72];
  __shared__ unsigned short Pl[8][16][72];
  int lin = blockIdx.x + 8 * blockIdx.y;
  int swz = (lin & 7) * 32 + (lin >> 3);  // each XCD owns 4 q-heads = 1 kv-head
  const int pair = swz & 7;
  const int h = swz >> 3;
  const int kh = h >> 2;
  const int tid = threadIdx.x, lane = tid & 63, wv = tid >> 6;
  const int lr = lane & 15, lg = lane >> 4;
  const int krow = tid >> 4, koff = (tid & 15) * 8;   // K rows krow, krow+32
  const int vrow = tid >> 3, voff = (tid & 7) * 8;    // V rows vrow, vrow+64
  const unsigned short* Kbase = Kb + (size_t)kh * S_LEN * HD;
  const unsigned short* Vbase = VTb + (size_t)kh * HD * S_LEN;

  for (int half = 0; half < 2; ++half) {
    const int qt = half ? 15 - pair : pair;
    const int q0 = qt * 128;
    const int nt = 2 * qt + 2;
    bf16x8 qf[4];
    {
      const unsigned short* qp = Qb + ((size_t)h * S_LEN + q0 + wv * 16 + lr) * HD + lg * 8;
#pragma unroll
      for (int s = 0; s < 4; ++s) qf[s] = *(const bf16x8*)(qp + s * 32);
    }
    f32x4 o[8];
#pragma unroll
    for (int i = 0; i < 8; ++i) o[i] = f32x4{0.f, 0.f, 0.f, 0.f};
    float mrow[4] = {-1e30f, -1e30f, -1e30f, -1e30f};
    float lrow[4] = {0.f, 0.f, 0.f, 0.f};

    u16x8 kreg[2], vreg[2];
    {
      const unsigned short* kp = Kbase + (size_t)krow * HD + koff;
      const unsigned short* vp = Vbase + (size_t)vrow * S_LEN + voff;
      kreg[0] = *(const u16x8*)kp;
      kreg[1] = *(const u16x8*)(kp + (size_t)32 * HD);
      vreg[0] = *(const u16x8*)vp;
      vreg[1] = *(const u16x8*)(vp + (size_t)64 * S_LEN);
    }
    __syncthreads();  // prior half's LDS readers done
    *(u16x8*)&Kl[krow][koff] = kreg[0];
    *(u16x8*)&Kl[krow + 32][koff] = kreg[1];
    *(u16x8*)&Vt[vrow][voff] = vreg[0];
    *(u16x8*)&Vt[vrow + 64][voff] = vreg[1];
    __syncthreads();

    for (int t = 0; t < nt; ++t) {
      if (t + 1 < nt) {  // T14: prefetch next tile into regs
        const unsigned short* kp = Kbase + ((size_t)(t + 1) * 64 + krow) * HD + koff;
        const unsigned short* vp = Vbase + (size_t)vrow * S_LEN + (t + 1) * 64 + voff;
        kreg[0] = *(const u16x8*)kp;
        kreg[1] = *(const u16x8*)(kp + (size_t)32 * HD);
        vreg[0] = *(const u16x8*)vp;
        vreg[1] = *(const u16x8*)(vp + (size_t)64 * S_LEN);
      }
      const int c0 = t * 64;
      const bool active = (c0 <= q0 + wv * 16 + 15);  // wave-uniform: skip fully-masked
      if (active) {
        f32x4 sf[4];
        __builtin_amdgcn_s_setprio(1);
#pragma unroll
        for (int c = 0; c < 4; ++c) {
          f32x4 s = {0.f, 0.f, 0.f, 0.f};
#pragma unroll
          for (int ss = 0; ss < 4; ++ss) {
            bf16x8 kf = *(const bf16x8*)&Kl[c * 16 + lr][ss * 32 + lg * 8];
            s = __builtin_amdgcn_mfma_f32_16x16x32_bf16(qf[ss], kf, s, 0, 0, 0);
          }
          sf[c] = s;
        }
        __builtin_amdgcn_s_setprio(0);

        if (t >= 2 * qt) {  // diagonal tiles only
#pragma unroll
          for (int c = 0; c < 4; ++c)
#pragma unroll
            for (int j = 0; j < 4; ++j)
              if ((c0 + c * 16 + lr) > (q0 + wv * 16 + lg * 4 + j)) sf[c][j] = -1e30f;
        }
        float tmax[4] = {-1e30f, -1e30f, -1e30f, -1e30f};
#pragma unroll
        for (int c = 0; c < 4; ++c)
#pragma unroll
          for (int j = 0; j < 4; ++j) tmax[j] = fmaxf(tmax[j], sf[c][j]);
#pragma unroll
        for (int dlt = 1; dlt < 16; dlt <<= 1)
#pragma unroll
          for (int j = 0; j < 4; ++j)
            tmax[j] = fmaxf(tmax[j], __shfl_xor(tmax[j], dlt, 64));

        // T13 defer-max: only rescale when max grows materially
        bool need = (tmax[0] > mrow[0] + 8.f) || (tmax[1] > mrow[1] + 8.f) ||
                    (tmax[2] > mrow[2] + 8.f) || (tmax[3] > mrow[3] + 8.f);
        if (__any(need)) {
          float alpha[4];
#pragma unroll
          for (int j = 0; j < 4; ++j) {
            float mn = fmaxf(mrow[j], tmax[j]);
            alpha[j] = exp2f(mrow[j] - mn);
            mrow[j] = mn;
          }
#pragma unroll
          for (int f = 0; f < 8; ++f)
#pragma unroll
            for (int j = 0; j < 4; ++j) o[f][j] *= alpha[j];
#pragma unroll
          for (int j = 0; j < 4; ++j) lrow[j] *= alpha[j];
        }
        float tsum[4] = {0.f, 0.f, 0.f, 0.f};
#pragma unroll
        for (int c = 0; c < 4; ++c)
#pragma unroll
          for (int j = 0; j < 4; ++j) {
            float pv = exp2f(sf[c][j] - mrow[j]);
            tsum[j] += pv;
            Pl[wv][lg * 4 + j][(c * 16 + lr) ^ ((lg & 2) << 2)] = f2bf(pv);
          }
#pragma unroll
        for (int dlt = 1; dlt < 16; dlt <<= 1)
#pragma unroll
          for (int j = 0; j < 4; ++j) tsum[j] += __shfl_xor(tsum[j], dlt, 64);
#pragma unroll
        for (int j = 0; j < 4; ++j) lrow[j] += tsum[j];

        // PV
        __builtin_amdgcn_s_setprio(1);
#pragma unroll
        for (int ks = 0; ks < 2; ++ks) {
          bf16x8 pa = *(const bf16x8*)&Pl[wv][lr][(ks * 32 + lg * 8) ^ (lr & 8)];
#pragma unroll
          for (int df = 0; df < 8; ++df) {
            bf16x8 vb = *(const bf16x8*)&Vt[df * 16 + lr][ks * 32 + lg * 8];
            o[df] = __builtin_amdgcn_mfma_f32_16x16x32_bf16(pa, vb, o[df], 0, 0, 0);
          }
        }
        __builtin_amdgcn_s_setprio(0);
      }

      if (t + 1 < nt) {
        __syncthreads();  // all waves done reading current tile
        *(u16x8*)&Kl[krow][koff] = kreg[0];
        *(u16x8*)&Kl[krow + 32][koff] = kreg[1];
        *(u16x8*)&Vt[vrow][voff] = vreg[0];
        *(u16x8*)&Vt[vrow + 64][voff] = vreg[1];
        __syncthreads();
      }
    }

#pragma unroll
    for (int j = 0; j < 4; ++j) {
      float inv = 1.0f / lrow[j];
      int row = q0 + wv * 16 + lg * 4 + j;
#pragma unroll
      for (int df = 0; df < 8; ++df)
        Ob[(size_t)row * (NH * HD) + h * HD + df * 16 + lr] = f2bf(o[df][j] * inv);
    }
  }
}

// ---------------- launch ----------------
extern "C" void kernel_launch(void* const* d_in, const int* in_sizes, int n_in,
                              void* d_out, int out_size, void* d_ws, size_t ws_size,
                              hipStream_t stream) {
  const float* hidden = (const float*)d_in[0];
  const float* wq = (const float*)d_in[1];
  const float* bq = (const float*)d_in[2];
  const float* wk = (const float*)d_in[3];
  const float* bk = (const float*)d_in[4];
  const float* wv = (const float*)d_in[5];
  const float* bv = (const float*)d_in[6];
  const float* wo = (const float*)d_in[7];
  float* out = (float*)d_out;

  char* p = (char*)d_ws;
  float* cs = (float*)p;                      p += (size_t)1 << 20;
  unsigned short* hb = (unsigned short*)p;    p += (size_t)16 << 20;
  unsigned short* Qb = (unsigned short*)p;    p += (size_t)16 << 20;
  unsigned short* Kbuf = (unsigned short*)p;  p += (size_t)4 << 20;
  unsigned short* VTb = (unsigned short*)p;   p += (size_t)4 << 20;
  unsigned short* attno = (unsigned short*)p; p += (size_t)16 << 20;
  unsigned short* wbuf = (unsigned short*)p;  // 48 MB reused (qkv weights, then wo)

  const float QSC = 0.08838834764831845f * 1.44269504088896340f;  // 1/sqrt(128)*log2e

  hipLaunchKernelGGL(rope_table, dim3(512), dim3(256), 0, stream, cs);
  hipLaunchKernelGGL(f2bf_kernel, dim3(4096), dim3(256), 0, stream, hidden, hb, S_LEN * HID / 8);
  hipLaunchKernelGGL(f2bf_kernel, dim3(8192), dim3(256), 0, stream, wq, wbuf, 4096 * HID / 8);
  hipLaunchKernelGGL(f2bf_kernel, dim3(2048), dim3(256), 0, stream, wk, wbuf + (size_t)4096 * HID, 1024 * HID / 8);
  hipLaunchKernelGGL(f2bf_kernel, dim3(2048), dim3(256), 0, stream, wv, wbuf + (size_t)5120 * HID, 1024 * HID / 8);
  hipLaunchKernelGGL((gemm_nt<1>), dim3(16, 48), dim3(256), 0, stream,
                     hb, wbuf, bq, bk, bv, Qb, Kbuf, VTb, (float*)nullptr);
  hipLaunchKernelGGL(rope_apply, dim3(16384), dim3(256), 0, stream, Qb, cs, QSC, NH * S_LEN * 64);
  hipLaunchKernelGGL(rope_apply, dim3(4096), dim3(256), 0, stream, Kbuf, cs, 1.0f, NKV * S_LEN * 64);
  hipLaunchKernelGGL(attn_fwd, dim3(8, 32), dim3(512), 0, stream, Qb, Kbuf, VTb, attno);
  hipLaunchKernelGGL(f2bf_kernel, dim3(8192), dim3(256), 0, stream, wo, wbuf, 4096 * HID / 8);
  hipLaunchKernelGGL((gemm_nt<0>), dim3(16, 32), dim3(256), 0, stream,
                     attno, wbuf, (const float*)nullptr, (const float*)nullptr, (const float*)nullptr,
                     (unsigned short*)nullptr, (unsigned short*)nullptr, (unsigned short*)nullptr, out);
}